// Round 1
// baseline (457.803 us; speedup 1.0000x reference)
//
#include <hip/hip_runtime.h>

typedef unsigned short ushort_t;
typedef __attribute__((ext_vector_type(8))) short bf16x8;
typedef __attribute__((ext_vector_type(4))) float f32x4;
typedef __attribute__((ext_vector_type(8))) unsigned short ushort8;

// Problem geometry (compile-time)
constexpr int BB   = 8;
constexpr int CC   = 256;
constexpr int OUTC = 256;
constexpr int KK   = 7;
constexpr int LL   = 2048;
constexpr int PADc = 3;
constexpr int KD   = CC * KK;        // 1792 reduction dim
constexpr int MOFF = CC * KK * 2;    // 3584 offset-conv out channels
constexpr int NTOT = BB * LL;        // 16384
constexpr int NKSTEPS = KD / 32;     // 56

__device__ __forceinline__ ushort_t f2bf(float f) {
    unsigned u = __float_as_uint(f);
    unsigned r = (u + 0x7fffu + ((u >> 16) & 1u)) >> 16;  // RNE
    return (ushort_t)r;
}
__device__ __forceinline__ float bf2f(ushort_t h) {
    return __uint_as_float(((unsigned)h) << 16);
}

// -------------------- cast f32 -> bf16 (vectorized) --------------------
__global__ __launch_bounds__(256) void cast_k(const float4* __restrict__ src,
                                              ushort_t* __restrict__ dst, int n4) {
    int i = blockIdx.x * 256 + threadIdx.x;
    if (i >= n4) return;
    float4 v = src[i];
    ushort4 o;
    o.x = f2bf(v.x); o.y = f2bf(v.y); o.z = f2bf(v.z); o.w = f2bf(v.w);
    *(ushort4*)(dst + (size_t)i * 4) = o;
}

// -------------------- im2col: xT[n][ck] = x[b, c, l-3+kk] --------------------
__global__ __launch_bounds__(256) void im2col_k(const ushort_t* __restrict__ xb,
                                                ushort_t* __restrict__ xT) {
    int n = blockIdx.x;                 // 0..16383
    int t = threadIdx.x;
    if (t >= 224) return;               // 224 * 8 = 1792
    int b = n >> 11, l = n & 2047;
    const ushort_t* xbb = xb + (size_t)b * (CC * LL);
    ushort8 v;
#pragma unroll
    for (int j = 0; j < 8; ++j) {
        int ck = t * 8 + j;
        int c = ck / 7;
        int kk = ck - c * 7;
        int p = l - PADc + kk;
        v[j] = ((unsigned)p < (unsigned)LL) ? xbb[c * LL + p] : (ushort_t)0;
    }
    *(ushort8*)(xT + (size_t)n * KD + t * 8) = v;
}

// -------------------- async global->LDS 16B --------------------
__device__ __forceinline__ void load_lds16(const ushort_t* g, ushort_t* l) {
    __builtin_amdgcn_global_load_lds(
        (const __attribute__((address_space(1))) unsigned int*)g,
        (__attribute__((address_space(3))) unsigned int*)l, 16, 0, 0);
}

// -------------------- GEMM: D[m][n] = sum_k A[m][k] * Bt[n][k] --------------------
// 128x128 tile, BK=32, 4 waves (2x2 of 64x64), mfma 16x16x32 bf16.
// LDS layout per buffer: A region [128 rows][4 slots of 16B], slot XOR-swizzled by (row&3);
// B region same, rows are n.  Staged with global_load_lds (lane*16 linear dest,
// swizzle applied on the per-lane GLOBAL source address).
__device__ __forceinline__ void stage_tile(ushort_t* lds_s,
                                           const ushort_t* __restrict__ A,
                                           const ushort_t* __restrict__ Bt,
                                           int m0, int n0, int buf, int kt,
                                           int wid, int lane) {
#pragma unroll
    for (int i = 0; i < 4; ++i) {
        int idx = wid * 4 + i;                 // 0..15; 0-7 = A (8KB), 8-15 = B
        int lin = idx * 1024 + lane * 16;      // byte offset within 16KB buffer
        const ushort_t* g;
        if (idx < 8) {
            int row  = lin >> 6;
            int slot = (lin >> 4) & 3;
            g = A + (size_t)(m0 + row) * KD + kt * 32 + ((slot ^ (row & 3)) << 3);
        } else {
            int lb   = lin - 8192;
            int row  = lb >> 6;
            int slot = (lb >> 4) & 3;
            g = Bt + (size_t)(n0 + row) * KD + kt * 32 + ((slot ^ (row & 3)) << 3);
        }
        load_lds16(g, lds_s + buf * 8192 + idx * 512);   // wave-uniform LDS base
    }
}

template <int EPI>  // 0: bf16 store to off[m][n] (+bvec), 1: f32 store to out[b][m][l] (+bvec)
__global__ __launch_bounds__(256) void gemm_bt(const ushort_t* __restrict__ A,
                                               const ushort_t* __restrict__ Bt,
                                               const float* __restrict__ bvec,
                                               ushort_t* __restrict__ Doff,
                                               float* __restrict__ Dout) {
    __shared__ __align__(16) ushort_t lds_s[2][8192];   // 2 bufs x (A 8KB + B 8KB)
    int mt = blockIdx.x >> 7;
    int nt = blockIdx.x & 127;
    int m0 = mt * 128, n0 = nt * 128;
    int tid = threadIdx.x;
    int wid = tid >> 6, lane = tid & 63;
    int wr = wid >> 1, wc = wid & 1;

    f32x4 acc[4][4] = {};

    stage_tile(&lds_s[0][0], A, Bt, m0, n0, 0, 0, wid, lane);
    __syncthreads();

    int r15 = lane & 15, kh = lane >> 4;
    int sw = ((kh ^ (r15 & 3)) << 3);   // swizzled 16B-slot offset (in ushorts)

    for (int kt = 0; kt < NKSTEPS; ++kt) {
        int cur = kt & 1;
        if (kt + 1 < NKSTEPS)
            stage_tile(&lds_s[0][0], A, Bt, m0, n0, cur ^ 1, kt + 1, wid, lane);

        const ushort_t* sA = &lds_s[cur][0];
        const ushort_t* sB = &lds_s[cur][4096];
        bf16x8 af[4], bq[4];
#pragma unroll
        for (int f = 0; f < 4; ++f) {
            af[f] = *(const bf16x8*)(sA + (wr * 64 + f * 16 + r15) * 32 + sw);
            bq[f] = *(const bf16x8*)(sB + (wc * 64 + f * 16 + r15) * 32 + sw);
        }
#pragma unroll
        for (int i = 0; i < 4; ++i)
#pragma unroll
            for (int j = 0; j < 4; ++j)
                acc[i][j] = __builtin_amdgcn_mfma_f32_16x16x32_bf16(af[i], bq[j], acc[i][j], 0, 0, 0);
        __syncthreads();
    }

    // epilogue: D[row=(lane>>4)*4+r][col=lane&15] per 16x16 fragment
    int rbase = (lane >> 4) * 4;
#pragma unroll
    for (int i = 0; i < 4; ++i) {
#pragma unroll
        for (int j = 0; j < 4; ++j) {
            int m = m0 + wr * 64 + i * 16 + rbase;
            int n = n0 + wc * 64 + j * 16 + r15;
            f32x4 v = acc[i][j];
#pragma unroll
            for (int r = 0; r < 4; ++r) {
                float val = v[r] + bvec[m + r];
                if (EPI == 0) {
                    Doff[(size_t)(m + r) * NTOT + n] = f2bf(val);
                } else {
                    int b = n >> 11, l = n & 2047;
                    Dout[((size_t)(b * OUTC + (m + r))) * LL + l] = val;
                }
            }
        }
    }
}

// -------------------- sampling: s[n][ck] = lerp(x, pos) * sigmoid(mask) --------------------
__global__ __launch_bounds__(256) void sample_k(const float* __restrict__ x,
                                                const ushort_t* __restrict__ off,
                                                ushort_t* __restrict__ s) {
    int lane = threadIdx.x & 63;
    int wv = threadIdx.x >> 6;
    int n = (blockIdx.x & 255) * 64 + lane;
    int cb = blockIdx.x >> 8;           // 0..6
    int b = n >> 11, l = n & 2047;
    const float* xb_ = x + (size_t)b * (CC * LL);
#pragma unroll 1
    for (int it = 0; it < 8; ++it) {
        int ck0 = cb * 256 + it * 32 + wv * 8;
        ushort8 o8;
#pragma unroll
        for (int j = 0; j < 8; ++j) {
            int ck = ck0 + j;
            int c = ck / 7;
            int kk = ck - c * 7;
            float offv = bf2f(off[(size_t)ck * NTOT + n]);
            float mpre = bf2f(off[(size_t)(KD + ck) * NTOT + n]);
            float mask = 1.0f / (1.0f + __expf(-mpre));
            float pos = offv + (float)(l - PADc + kk);
            float p0f = floorf(pos);
            float frac = pos - p0f;
            int p0 = (int)p0f;
            const float* xr = xb_ + (size_t)c * LL;
            float x0 = ((unsigned)p0 < (unsigned)LL) ? xr[p0] : 0.0f;
            float x1 = ((unsigned)(p0 + 1) < (unsigned)LL) ? xr[p0 + 1] : 0.0f;
            float v = (x0 + (x1 - x0) * frac) * mask;
            o8[j] = f2bf(v);
        }
        *(ushort8*)(s + (size_t)n * KD + ck0) = o8;
    }
}

// -------------------- launch --------------------
extern "C" void kernel_launch(void* const* d_in, const int* in_sizes, int n_in,
                              void* d_out, int out_size, void* d_ws, size_t ws_size,
                              hipStream_t stream) {
    const float* x      = (const float*)d_in[0];   // (8,256,2048)
    const float* w_off  = (const float*)d_in[1];   // (3584,256,7)
    const float* b_off  = (const float*)d_in[2];   // (3584,)
    const float* weight = (const float*)d_in[3];   // (256,256,7)
    const float* bias   = (const float*)d_in[4];   // (256,)
    float* out = (float*)d_out;                    // (8,256,2048)

    ushort_t* w = (ushort_t*)d_ws;
    ushort_t* xb  = w;                       // 4,194,304
    ushort_t* wb  = xb  + 4194304;           // 6,422,528
    ushort_t* wtb = wb  + 6422528;           //   458,752
    ushort_t* xT  = wtb + 458752;            // 29,360,128  [n][ck]
    ushort_t* off = xT  + 29360128;          // 58,720,256  [oc][n]
    ushort_t* s   = off + 58720256;          // 29,360,128  [n][ck]

    cast_k<<<(1048576 + 255) / 256, 256, 0, stream>>>((const float4*)x, xb, 1048576);
    cast_k<<<(1605632 + 255) / 256, 256, 0, stream>>>((const float4*)w_off, wb, 1605632);
    cast_k<<<(114688 + 255) / 256, 256, 0, stream>>>((const float4*)weight, wtb, 114688);

    im2col_k<<<NTOT, 256, 0, stream>>>(xb, xT);

    // offset conv: [3584 x 1792] * [1792 x 16384]
    gemm_bt<0><<<(MOFF / 128) * 128, 256, 0, stream>>>(wb, xT, b_off, off, nullptr);

    // deformable sampling
    sample_k<<<256 * 7, 256, 0, stream>>>(x, off, s);

    // main conv: [256 x 1792] * [1792 x 16384]
    gemm_bt<1><<<(OUTC / 128) * 128, 256, 0, stream>>>(wtb, s, bias, nullptr, out);
}

// Round 2
// 406.346 us; speedup vs baseline: 1.1266x; 1.1266x over previous
//
#include <hip/hip_runtime.h>

typedef unsigned short ushort_t;
typedef __attribute__((ext_vector_type(8))) short bf16x8;
typedef __attribute__((ext_vector_type(4))) float f32x4;
typedef __attribute__((ext_vector_type(8))) unsigned short ushort8;

// Problem geometry (compile-time)
constexpr int BB   = 8;
constexpr int CC   = 256;
constexpr int OUTC = 256;
constexpr int KK   = 7;
constexpr int LL   = 2048;
constexpr int PADc = 3;
constexpr int KD   = CC * KK;        // 1792 reduction dim
constexpr int MOFF = CC * KK * 2;    // 3584 offset-conv out channels
constexpr int NTOT = BB * LL;        // 16384
constexpr int NKSTEPS = KD / 32;     // 56

__device__ __forceinline__ ushort_t f2bf(float f) {
    unsigned u = __float_as_uint(f);
    unsigned r = (u + 0x7fffu + ((u >> 16) & 1u)) >> 16;  // RNE
    return (ushort_t)r;
}
__device__ __forceinline__ float bf2f(ushort_t h) {
    return __uint_as_float(((unsigned)h) << 16);
}

// -------------------- cast f32 -> bf16 (vectorized) --------------------
__global__ __launch_bounds__(256) void cast_k(const float4* __restrict__ src,
                                              ushort_t* __restrict__ dst, int n4) {
    int i = blockIdx.x * 256 + threadIdx.x;
    if (i >= n4) return;
    float4 v = src[i];
    ushort4 o;
    o.x = f2bf(v.x); o.y = f2bf(v.y); o.z = f2bf(v.z); o.w = f2bf(v.w);
    *(ushort4*)(dst + (size_t)i * 4) = o;
}

// -------------------- im2col: xT[n][ck] = x[b, c, l-3+kk] --------------------
__global__ __launch_bounds__(256) void im2col_k(const ushort_t* __restrict__ xb,
                                                ushort_t* __restrict__ xT) {
    int n = blockIdx.x;                 // 0..16383
    int t = threadIdx.x;
    if (t >= 224) return;               // 224 * 8 = 1792
    int b = n >> 11, l = n & 2047;
    const ushort_t* xbb = xb + (size_t)b * (CC * LL);
    ushort8 v;
#pragma unroll
    for (int j = 0; j < 8; ++j) {
        int ck = t * 8 + j;
        int c = ck / 7;
        int kk = ck - c * 7;
        int p = l - PADc + kk;
        v[j] = ((unsigned)p < (unsigned)LL) ? xbb[c * LL + p] : (ushort_t)0;
    }
    *(ushort8*)(xT + (size_t)n * KD + t * 8) = v;
}

// -------------------- async global->LDS 16B --------------------
__device__ __forceinline__ void load_lds16(const ushort_t* g, ushort_t* l) {
    __builtin_amdgcn_global_load_lds(
        (const __attribute__((address_space(1))) unsigned int*)g,
        (__attribute__((address_space(3))) unsigned int*)l, 16, 0, 0);
}

// ==================== 256x256 counted-vmcnt GEMM (GEMM1) ====================
// D[m][n] = sum_k A[m][k]*Bt[n][k] + bvec[m], bf16 out to Doff[m][n].
// 8 waves (2M x 4N), per-wave 128x64 (acc[8][4]), BK=32, 4-buffer LDS ring
// (4 x 32KB = 128KB), raw s_barrier + counted vmcnt(8) (3 tiles in flight),
// setprio around MFMA cluster.  LDS slot swizzle: u = g ^ ((row>>1)&3)
// (2-way bank aliasing = free), applied on pre-swizzled global source
// (global_load_lds dest must stay linear) and on the ds_read side.
__device__ __forceinline__ void stage256(ushort_t* ldsbuf,
                                         const ushort_t* __restrict__ A,
                                         const ushort_t* __restrict__ Bt,
                                         int m0, int n0, int kt,
                                         int wid, int lane) {
    int t = wid * 64 + lane;
    int g = (t & 3) ^ ((t >> 3) & 3);        // pre-swizzled global 16B-slot
#pragma unroll
    for (int j = 0; j < 2; ++j) {
        int row = j * 128 + (t >> 2);
        // LDS dest: wave-uniform base; HW adds lane*16B
        load_lds16(A  + (size_t)(m0 + row) * KD + kt * 32 + g * 8,
                   ldsbuf + j * 4096 + wid * 512);
        load_lds16(Bt + (size_t)(n0 + row) * KD + kt * 32 + g * 8,
                   ldsbuf + 8192 + j * 4096 + wid * 512);
    }
}

template <int VMC>
__device__ __forceinline__ void kstep256(const ushort_t* __restrict__ A,
                                         const ushort_t* __restrict__ Bt,
                                         ushort_t* lds, int m0, int n0, int kt,
                                         int wid, int lane, int wr, int wc,
                                         int r15, int u, f32x4 (&acc)[8][4]) {
    asm volatile("s_waitcnt vmcnt(%0)" :: "n"(VMC) : "memory");
    __builtin_amdgcn_s_barrier();
    const ushort_t* buf = lds + (size_t)(kt & 3) * 16384;
    const ushort_t* pa = buf + (wr * 128 + r15) * 32 + u * 8;
    const ushort_t* pb = buf + 8192 + (wc * 64 + r15) * 32 + u * 8;
    bf16x8 af[8], bq[4];
#pragma unroll
    for (int i = 0; i < 8; ++i) af[i] = *(const bf16x8*)(pa + i * 512);
#pragma unroll
    for (int j = 0; j < 4; ++j) bq[j] = *(const bf16x8*)(pb + j * 512);
    if (kt + 3 < NKSTEPS)
        stage256(lds + (size_t)((kt + 3) & 3) * 16384, A, Bt, m0, n0, kt + 3, wid, lane);
    __builtin_amdgcn_s_setprio(1);
#pragma unroll
    for (int i = 0; i < 8; ++i)
#pragma unroll
        for (int j = 0; j < 4; ++j)
            acc[i][j] = __builtin_amdgcn_mfma_f32_16x16x32_bf16(af[i], bq[j], acc[i][j], 0, 0, 0);
    __builtin_amdgcn_s_setprio(0);
}

__global__ __launch_bounds__(512, 2) void gemm256_off(const ushort_t* __restrict__ A,
                                                      const ushort_t* __restrict__ Bt,
                                                      const float* __restrict__ bvec,
                                                      ushort_t* __restrict__ Doff) {
    __shared__ __align__(16) ushort_t lds[4 * 16384];   // 128 KiB ring
    constexpr int NT = NTOT / 256;                       // 64 n-tiles
    constexpr int NWG = (MOFF / 256) * NT;               // 896 (%8==0)
    int bid = blockIdx.x;
    int wg = (bid & 7) * (NWG / 8) + (bid >> 3);         // XCD-bijective swizzle
    int mt = wg / NT, nt = wg % NT;
    int m0 = mt * 256, n0 = nt * 256;
    int tid = threadIdx.x, wid = tid >> 6, lane = tid & 63;
    int wr = wid >> 2, wc = wid & 3;
    int r15 = lane & 15, kh = lane >> 4;
    int u = kh ^ ((r15 >> 1) & 3);                       // swizzled read slot

    f32x4 acc[8][4] = {};

    stage256(lds,             A, Bt, m0, n0, 0, wid, lane);
    stage256(lds + 16384,     A, Bt, m0, n0, 1, wid, lane);
    stage256(lds + 2 * 16384, A, Bt, m0, n0, 2, wid, lane);

    for (int kt = 0; kt < NKSTEPS - 2; ++kt)
        kstep256<8>(A, Bt, lds, m0, n0, kt, wid, lane, wr, wc, r15, u, acc);
    kstep256<4>(A, Bt, lds, m0, n0, NKSTEPS - 2, wid, lane, wr, wc, r15, u, acc);
    kstep256<0>(A, Bt, lds, m0, n0, NKSTEPS - 1, wid, lane, wr, wc, r15, u, acc);

    int rbase = kh * 4;
#pragma unroll
    for (int i = 0; i < 8; ++i)
#pragma unroll
        for (int j = 0; j < 4; ++j) {
            int m = m0 + wr * 128 + i * 16 + rbase;
            int n = n0 + wc * 64 + j * 16 + r15;
#pragma unroll
            for (int r = 0; r < 4; ++r) {
                float val = acc[i][j][r] + bvec[m + r];
                Doff[(size_t)(m + r) * NTOT + n] = f2bf(val);
            }
        }
}

// ==================== 128x128 GEMM (kept for the small main conv) ====================
__device__ __forceinline__ void stage_tile(ushort_t* lds_s,
                                           const ushort_t* __restrict__ A,
                                           const ushort_t* __restrict__ Bt,
                                           int m0, int n0, int buf, int kt,
                                           int wid, int lane) {
#pragma unroll
    for (int i = 0; i < 4; ++i) {
        int idx = wid * 4 + i;                 // 0..15; 0-7 = A (8KB), 8-15 = B
        int lin = idx * 1024 + lane * 16;      // byte offset within 16KB buffer
        const ushort_t* g;
        if (idx < 8) {
            int row  = lin >> 6;
            int slot = (lin >> 4) & 3;
            g = A + (size_t)(m0 + row) * KD + kt * 32 + ((slot ^ (row & 3)) << 3);
        } else {
            int lb   = lin - 8192;
            int row  = lb >> 6;
            int slot = (lb >> 4) & 3;
            g = Bt + (size_t)(n0 + row) * KD + kt * 32 + ((slot ^ (row & 3)) << 3);
        }
        load_lds16(g, lds_s + buf * 8192 + idx * 512);   // wave-uniform LDS base
    }
}

__global__ __launch_bounds__(256) void gemm_bt_out(const ushort_t* __restrict__ A,
                                                   const ushort_t* __restrict__ Bt,
                                                   const float* __restrict__ bvec,
                                                   float* __restrict__ Dout) {
    __shared__ __align__(16) ushort_t lds_s[2][8192];   // 2 bufs x (A 8KB + B 8KB)
    int mt = blockIdx.x >> 7;
    int nt = blockIdx.x & 127;
    int m0 = mt * 128, n0 = nt * 128;
    int tid = threadIdx.x;
    int wid = tid >> 6, lane = tid & 63;
    int wr = wid >> 1, wc = wid & 1;

    f32x4 acc[4][4] = {};

    stage_tile(&lds_s[0][0], A, Bt, m0, n0, 0, 0, wid, lane);
    __syncthreads();

    int r15 = lane & 15, kh = lane >> 4;
    int sw = ((kh ^ (r15 & 3)) << 3);   // swizzled 16B-slot offset (in ushorts)

    for (int kt = 0; kt < NKSTEPS; ++kt) {
        int cur = kt & 1;
        if (kt + 1 < NKSTEPS)
            stage_tile(&lds_s[0][0], A, Bt, m0, n0, cur ^ 1, kt + 1, wid, lane);

        const ushort_t* sA = &lds_s[cur][0];
        const ushort_t* sB = &lds_s[cur][4096];
        bf16x8 af[4], bq[4];
#pragma unroll
        for (int f = 0; f < 4; ++f) {
            af[f] = *(const bf16x8*)(sA + (wr * 64 + f * 16 + r15) * 32 + sw);
            bq[f] = *(const bf16x8*)(sB + (wc * 64 + f * 16 + r15) * 32 + sw);
        }
#pragma unroll
        for (int i = 0; i < 4; ++i)
#pragma unroll
            for (int j = 0; j < 4; ++j)
                acc[i][j] = __builtin_amdgcn_mfma_f32_16x16x32_bf16(af[i], bq[j], acc[i][j], 0, 0, 0);
        __syncthreads();
    }

    int rbase = (lane >> 4) * 4;
#pragma unroll
    for (int i = 0; i < 4; ++i) {
#pragma unroll
        for (int j = 0; j < 4; ++j) {
            int m = m0 + wr * 64 + i * 16 + rbase;
            int n = n0 + wc * 64 + j * 16 + r15;
            f32x4 v = acc[i][j];
#pragma unroll
            for (int r = 0; r < 4; ++r) {
                float val = v[r] + bvec[m + r];
                int b = n >> 11, l = n & 2047;
                Dout[((size_t)(b * OUTC + (m + r))) * LL + l] = val;
            }
        }
    }
}

// -------------------- sampling: s[n][ck] = lerp(x, pos) * sigmoid(mask) --------------------
__global__ __launch_bounds__(256) void sample_k(const float* __restrict__ x,
                                                const ushort_t* __restrict__ off,
                                                ushort_t* __restrict__ s) {
    int lane = threadIdx.x & 63;
    int wv = threadIdx.x >> 6;
    int n = (blockIdx.x & 255) * 64 + lane;
    int cb = blockIdx.x >> 8;           // 0..6
    int b = n >> 11, l = n & 2047;
    const float* xb_ = x + (size_t)b * (CC * LL);
#pragma unroll 1
    for (int it = 0; it < 8; ++it) {
        int ck0 = cb * 256 + it * 32 + wv * 8;
        ushort8 o8;
#pragma unroll
        for (int j = 0; j < 8; ++j) {
            int ck = ck0 + j;
            int c = ck / 7;
            int kk = ck - c * 7;
            float offv = bf2f(off[(size_t)ck * NTOT + n]);
            float mpre = bf2f(off[(size_t)(KD + ck) * NTOT + n]);
            float mask = 1.0f / (1.0f + __expf(-mpre));
            float pos = offv + (float)(l - PADc + kk);
            float p0f = floorf(pos);
            float frac = pos - p0f;
            int p0 = (int)p0f;
            const float* xr = xb_ + (size_t)c * LL;
            float x0 = ((unsigned)p0 < (unsigned)LL) ? xr[p0] : 0.0f;
            float x1 = ((unsigned)(p0 + 1) < (unsigned)LL) ? xr[p0 + 1] : 0.0f;
            float v = (x0 + (x1 - x0) * frac) * mask;
            o8[j] = f2bf(v);
        }
        *(ushort8*)(s + (size_t)n * KD + ck0) = o8;
    }
}

// -------------------- launch --------------------
extern "C" void kernel_launch(void* const* d_in, const int* in_sizes, int n_in,
                              void* d_out, int out_size, void* d_ws, size_t ws_size,
                              hipStream_t stream) {
    const float* x      = (const float*)d_in[0];   // (8,256,2048)
    const float* w_off  = (const float*)d_in[1];   // (3584,256,7)
    const float* b_off  = (const float*)d_in[2];   // (3584,)
    const float* weight = (const float*)d_in[3];   // (256,256,7)
    const float* bias   = (const float*)d_in[4];   // (256,)
    float* out = (float*)d_out;                    // (8,256,2048)

    ushort_t* w = (ushort_t*)d_ws;
    ushort_t* xb  = w;                       // 4,194,304
    ushort_t* wb  = xb  + 4194304;           // 6,422,528
    ushort_t* wtb = wb  + 6422528;           //   458,752
    ushort_t* xT  = wtb + 458752;            // 29,360,128  [n][ck]
    ushort_t* off = xT  + 29360128;          // 58,720,256  [oc][n]
    ushort_t* s   = off + 58720256;          // 29,360,128  [n][ck]

    cast_k<<<(1048576 + 255) / 256, 256, 0, stream>>>((const float4*)x, xb, 1048576);
    cast_k<<<(1605632 + 255) / 256, 256, 0, stream>>>((const float4*)w_off, wb, 1605632);
    cast_k<<<(114688 + 255) / 256, 256, 0, stream>>>((const float4*)weight, wtb, 114688);

    im2col_k<<<NTOT, 256, 0, stream>>>(xb, xT);

    // offset conv: [3584 x 1792] * [1792 x 16384]  (256^2 counted-vmcnt GEMM)
    gemm256_off<<<(MOFF / 256) * (NTOT / 256), 512, 0, stream>>>(wb, xT, b_off, off);

    // deformable sampling
    sample_k<<<256 * 7, 256, 0, stream>>>(x, off, s);

    // main conv: [256 x 1792] * [1792 x 16384]
    gemm_bt_out<<<(OUTC / 128) * 128, 256, 0, stream>>>(wtb, s, bias, out);
}